// Round 1
// 1259.288 us; speedup vs baseline: 1.0350x; 1.0350x over previous
//
#include <hip/hip_runtime.h>
#include <hip/hip_bf16.h>

// Stable partition-by-species of two feature arrays.
//   feat_a [N,128] f32, feat_b [N,64] f32, species [N] i32 (values 0..3)
// Output: feat_a rows in stable-sorted-by-species order (N*128 floats),
// then feat_b rows likewise (N*64 floats).
//
// Plan: per-chunk histograms -> int4 wave-shuffle scan (2 barriers) ->
//       rank + nontemporal float4 row scatter.

#define CHUNK 256          // atoms per block (block = 256 threads)
#define NSPEC 4
#define SCAN_T 1024
#define SCAN_CPT 4         // chunks per scan thread (4096 chunks / 1024 threads)

typedef float __attribute__((ext_vector_type(4))) f32x4;

// ---------------------------------------------------------------- kernel 1
__global__ __launch_bounds__(256) void cs_hist(const int* __restrict__ species,
                                               int* __restrict__ counts,
                                               int num_chunks) {
    const int chunk = blockIdx.x;
    const int tid   = threadIdx.x;
    const int s     = species[chunk * CHUNK + tid];

    const int lane = tid & 63;
    const int wave = tid >> 6;
    __shared__ int wcnt[4][NSPEC];   // [wave][species]

    unsigned long long m0 = __ballot(s == 0);
    unsigned long long m1 = __ballot(s == 1);
    unsigned long long m2 = __ballot(s == 2);
    unsigned long long m3 = __ballot(s == 3);
    if (lane == 0) {
        wcnt[wave][0] = __popcll(m0);
        wcnt[wave][1] = __popcll(m1);
        wcnt[wave][2] = __popcll(m2);
        wcnt[wave][3] = __popcll(m3);
    }
    __syncthreads();
    if (tid < NSPEC) {
        counts[chunk * NSPEC + tid] =
            wcnt[0][tid] + wcnt[1][tid] + wcnt[2][tid] + wcnt[3][tid];
    }
}

// ---------------------------------------------------------------- kernel 2
// Single block, 1024 threads. counts[chunk] is an int4 (one lane per species).
// Scans all 4 species simultaneously: per-thread serial sum over SCAN_CPT
// chunks, wave-level inclusive scan via __shfl_up (no barriers), 16 wave
// sums combined through LDS (2 barriers total), then writeback of the
// global starting row offset for each (chunk, species).
__global__ __launch_bounds__(1024) void cs_scan(int* __restrict__ counts,
                                                int num_chunks) {
    const int tid  = threadIdx.x;
    const int lane = tid & 63;
    const int wave = tid >> 6;           // 0..15

    int4* c4 = (int4*)counts;

    int4 local[SCAN_CPT];
    int4 sum = make_int4(0, 0, 0, 0);
    #pragma unroll
    for (int k = 0; k < SCAN_CPT; ++k) {
        int c = tid * SCAN_CPT + k;
        int4 v = make_int4(0, 0, 0, 0);
        if (c < num_chunks) v = c4[c];
        local[k] = v;
        sum.x += v.x; sum.y += v.y; sum.z += v.z; sum.w += v.w;
    }

    // wave-level (64-lane) inclusive scan of int4
    int4 incl = sum;
    #pragma unroll
    for (int off = 1; off < 64; off <<= 1) {
        int ux = __shfl_up(incl.x, off);
        int uy = __shfl_up(incl.y, off);
        int uz = __shfl_up(incl.z, off);
        int uw = __shfl_up(incl.w, off);
        if (lane >= off) { incl.x += ux; incl.y += uy; incl.z += uz; incl.w += uw; }
    }

    __shared__ int4 wsum[16];
    __shared__ int4 stot;
    if (lane == 63) wsum[wave] = incl;
    __syncthreads();

    int4 woff = make_int4(0, 0, 0, 0);
    for (int w = 0; w < wave; ++w) {
        int4 t = wsum[w];
        woff.x += t.x; woff.y += t.y; woff.z += t.z; woff.w += t.w;
    }
    incl.x += woff.x; incl.y += woff.y; incl.z += woff.z; incl.w += woff.w;

    if (tid == SCAN_T - 1) stot = incl;   // grand total per species
    __syncthreads();

    int4 excl = make_int4(incl.x - sum.x, incl.y - sum.y,
                          incl.z - sum.z, incl.w - sum.w);

    const int4 tot = stot;
    int4 run;
    run.x = 0                           + excl.x;
    run.y = tot.x                       + excl.y;
    run.z = tot.x + tot.y               + excl.z;
    run.w = tot.x + tot.y + tot.z       + excl.w;

    #pragma unroll
    for (int k = 0; k < SCAN_CPT; ++k) {
        int c = tid * SCAN_CPT + k;
        if (c < num_chunks) {
            int4 v = local[k];
            c4[c] = run;
            run.x += v.x; run.y += v.y; run.z += v.z; run.w += v.w;
        }
    }
}

// ---------------------------------------------------------------- kernel 3
// offs[chunk][s] = global starting row for that (chunk, species).
// dest row for atom i = offs[chunk][s_i] + stable local rank of i among
// same-species atoms in the chunk. Pure streaming copy -> nontemporal.
__global__ __launch_bounds__(256) void cs_scatter(const f32x4* __restrict__ fa,
                                                  const f32x4* __restrict__ fb,
                                                  const int* __restrict__ species,
                                                  const int* __restrict__ offs,
                                                  f32x4* __restrict__ out,
                                                  int n) {
    const int chunk = blockIdx.x;
    const int tid   = threadIdx.x;
    const int atom  = chunk * CHUNK + tid;
    const int s     = species[atom];

    const int lane = tid & 63;
    const int wave = tid >> 6;

    __shared__ int wcnt[4][NSPEC];   // per-wave per-species counts
    __shared__ int dest[CHUNK];      // destination row per atom

    unsigned long long m0 = __ballot(s == 0);
    unsigned long long m1 = __ballot(s == 1);
    unsigned long long m2 = __ballot(s == 2);
    unsigned long long m3 = __ballot(s == 3);
    if (lane == 0) {
        wcnt[wave][0] = __popcll(m0);
        wcnt[wave][1] = __popcll(m1);
        wcnt[wave][2] = __popcll(m2);
        wcnt[wave][3] = __popcll(m3);
    }
    __syncthreads();

    unsigned long long ms = (s == 0) ? m0 : (s == 1) ? m1 : (s == 2) ? m2 : m3;
    unsigned long long lanemask = (lane == 0) ? 0ull : ((1ull << lane) - 1ull);
    int rank = __popcll(ms & lanemask);
    for (int w = 0; w < wave; ++w) rank += wcnt[w][s];

    dest[tid] = offs[chunk * NSPEC + s] + rank;
    __syncthreads();

    // ---- copy feat_a rows: 128 f32 = 32 float4 per row ----
    const f32x4* srcA = fa + (size_t)chunk * CHUNK * 32;
    #pragma unroll 8
    for (int i = tid; i < CHUNK * 32; i += 256) {
        int a = i >> 5, c = i & 31;
        f32x4 v = __builtin_nontemporal_load(&srcA[i]);
        __builtin_nontemporal_store(v, &out[(size_t)dest[a] * 32 + c]);
    }

    // ---- copy feat_b rows: 64 f32 = 16 float4 per row ----
    const f32x4* srcB = fb + (size_t)chunk * CHUNK * 16;
    f32x4* outB = out + (size_t)n * 32;   // after N*128 floats of out_a
    #pragma unroll 8
    for (int i = tid; i < CHUNK * 16; i += 256) {
        int a = i >> 4, c = i & 15;
        f32x4 v = __builtin_nontemporal_load(&srcB[i]);
        __builtin_nontemporal_store(v, &outB[(size_t)dest[a] * 16 + c]);
    }
}

// ---------------------------------------------------------------- launch
extern "C" void kernel_launch(void* const* d_in, const int* in_sizes, int n_in,
                              void* d_out, int out_size, void* d_ws, size_t ws_size,
                              hipStream_t stream) {
    const float* feat_a  = (const float*)d_in[0];
    const float* feat_b  = (const float*)d_in[1];
    const int*   species = (const int*)d_in[2];
    float*       out     = (float*)d_out;

    const int n = in_sizes[2];            // 1048576, divisible by CHUNK
    const int num_chunks = n / CHUNK;     // 4096

    int* counts = (int*)d_ws;             // num_chunks * 4 ints = 64 KB

    cs_hist<<<num_chunks, 256, 0, stream>>>(species, counts, num_chunks);
    cs_scan<<<1, SCAN_T, 0, stream>>>(counts, num_chunks);
    cs_scatter<<<num_chunks, 256, 0, stream>>>((const f32x4*)feat_a,
                                               (const f32x4*)feat_b,
                                               species, counts,
                                               (f32x4*)out, n);
}